// Round 1
// baseline (1657.389 us; speedup 1.0000x reference)
//
#include <hip/hip_runtime.h>
#include <hip/hip_bf16.h>
#include <math.h>

#define DD 64
#define HW_SHIFT 14           // H*W = 16384 (B=8, H=W=128 fixed instance)
#define HW_MASK 16383
#define TEMP_INV 14.285714285714285714f   // 1/0.07
#define M0F TEMP_INV

#define NCP 16   // pos chunks
#define NCN 64   // neg chunks
#define NB_AP 16
#define NB_AN 64

// ---------------- gather + L2 normalize (one wave per row) ----------------
__global__ void k_norm(const float* __restrict__ z, const int* __restrict__ idx,
                       int count, float* __restrict__ out) {
    int w = blockIdx.x * (blockDim.x >> 6) + (threadIdx.x >> 6);
    int lane = threadIdx.x & 63;
    if (w >= count) return;
    int n = idx[w];
    int b = n >> HW_SHIFT;
    int hw = n & HW_MASK;
    float v = z[((size_t)(b * DD + lane) << HW_SHIFT) + hw];
    float ss = v * v;
#pragma unroll
    for (int o = 32; o >= 1; o >>= 1) ss += __shfl_xor(ss, o, 64);
    float nn = sqrtf(ss);
    float denom = fmaxf(nn, 1e-12f);
    out[((size_t)w << 6) + lane] = v / denom;
}

// ---------------- gather anchors from normalized pos ----------------
__global__ void k_gather(const float* __restrict__ posN, const int* __restrict__ aidx,
                         int A, float* __restrict__ anc) {
    int t = blockIdx.x * blockDim.x + threadIdx.x;
    if (t >= A * DD) return;
    int a = t >> 6, d = t & 63;
    anc[t] = posN[((size_t)aidx[a] << 6) + d];
}

// ---------------- similarity reduction: lane <-> anchor ----------------
// MODE 0: max over pos candidates, excluding candidate index == anchor row index
// MODE 1: sum of exp(logit - M0) over neg candidates
template <int MODE>
__global__ void __launch_bounds__(256) k_sim(const float* __restrict__ anc, int A,
                      const float* __restrict__ cand, int count,
                      float* __restrict__ partial) {
    int tile = blockIdx.x * (blockDim.x >> 6) + (threadIdx.x >> 6);
    int lane = threadIdx.x & 63;
    int a = tile * 64 + lane;
    int nchunks = gridDim.y;
    int chunk = blockIdx.y;
    int per = (count + nchunks - 1) / nchunks;
    int c0 = chunk * per;
    int c1 = min(count, c0 + per);

    float av[64];
    {
        const float4* ar = (const float4*)(anc + ((size_t)a << 6));
#pragma unroll
        for (int j = 0; j < 16; ++j) {
            float4 q = ar[j];
            av[4 * j] = q.x; av[4 * j + 1] = q.y; av[4 * j + 2] = q.z; av[4 * j + 3] = q.w;
        }
    }

    float m = -__builtin_inff();
    float s = 0.f;
    int c = c0;
    for (; c + 1 < c1; c += 2) {
        const float* __restrict__ p0 = cand + ((size_t)c << 6);
        const float* __restrict__ p1 = p0 + 64;
        float d00 = 0, d01 = 0, d02 = 0, d03 = 0;
        float d10 = 0, d11 = 0, d12 = 0, d13 = 0;
#pragma unroll
        for (int j = 0; j < 64; j += 4) {
            d00 += av[j]     * p0[j];     d10 += av[j]     * p1[j];
            d01 += av[j + 1] * p0[j + 1]; d11 += av[j + 1] * p1[j + 1];
            d02 += av[j + 2] * p0[j + 2]; d12 += av[j + 2] * p1[j + 2];
            d03 += av[j + 3] * p0[j + 3]; d13 += av[j + 3] * p1[j + 3];
        }
        float dot0 = (d00 + d01) + (d02 + d03);
        float dot1 = (d10 + d11) + (d12 + d13);
        float l0 = dot0 * TEMP_INV;
        float l1 = dot1 * TEMP_INV;
        if (MODE == 0) {
            if (c == a)     l0 = -__builtin_inff();
            if (c + 1 == a) l1 = -__builtin_inff();
            m = fmaxf(m, fmaxf(l0, l1));
        } else {
            s += __expf(l0 - M0F) + __expf(l1 - M0F);
        }
    }
    for (; c < c1; ++c) {
        const float* __restrict__ p0 = cand + ((size_t)c << 6);
        float d0 = 0, d1 = 0, d2 = 0, d3 = 0;
#pragma unroll
        for (int j = 0; j < 64; j += 4) {
            d0 += av[j] * p0[j]; d1 += av[j + 1] * p0[j + 1];
            d2 += av[j + 2] * p0[j + 2]; d3 += av[j + 3] * p0[j + 3];
        }
        float dot = (d0 + d1) + (d2 + d3);
        float l = dot * TEMP_INV;
        if (MODE == 0) {
            if (c == a) l = -__builtin_inff();
            m = fmaxf(m, l);
        } else {
            s += __expf(l - M0F);
        }
    }
    if (a < A) partial[(size_t)chunk * A + a] = (MODE == 0) ? m : s;
}

// ---------------- combine partials -> per-block loss sums ----------------
__global__ void k_combine(const float* __restrict__ posmax, int ncp,
                          const float* __restrict__ negsum, int ncn,
                          int A, float* __restrict__ lossPartial) {
    int a = blockIdx.x * blockDim.x + threadIdx.x;
    float term = 0.f;
    if (a < A) {
        float m = -__builtin_inff();
        for (int k = 0; k < ncp; ++k) m = fmaxf(m, posmax[(size_t)k * A + a]);
        float s = 0.f;
        for (int k = 0; k < ncn; ++k) s += negsum[(size_t)k * A + a];
        float total = __expf(m - M0F) + s;
        term = M0F + logf(total) - m;   // lse - pos_sim
    }
    __shared__ float red[256];
    red[threadIdx.x] = term;
    __syncthreads();
    for (int o = 128; o >= 1; o >>= 1) {
        if (threadIdx.x < o) red[threadIdx.x] += red[threadIdx.x + o];
        __syncthreads();
    }
    if (threadIdx.x == 0) lossPartial[blockIdx.x] = red[0];
}

// ---------------- column sums (deterministic two-stage) ----------------
__global__ void k_colsum(const float* __restrict__ in, int rows, float* __restrict__ partial) {
    int d = threadIdx.x & 63;
    int rg = threadIdx.x >> 6;
    float acc = 0.f;
    for (int r = blockIdx.x * 4 + rg; r < rows; r += gridDim.x * 4)
        acc += in[((size_t)r << 6) + d];
    __shared__ float red[256];
    red[threadIdx.x] = acc;
    __syncthreads();
    if (rg == 0)
        partial[((size_t)blockIdx.x << 6) + d] = (red[d] + red[64 + d]) + (red[128 + d] + red[192 + d]);
}

__global__ void k_colsum_final(const float* __restrict__ partial, int nb, float* __restrict__ out64) {
    int d = threadIdx.x;
    if (d >= 64) return;
    float acc = 0.f;
    for (int k = 0; k < nb; ++k) acc += partial[((size_t)k << 6) + d];
    out64[d] = acc;
}

// ---------------- accuracy comparisons ----------------
__global__ void k_acc(const float* __restrict__ ap, int nap, int nan_,
                      const float* __restrict__ Sp, const float* __restrict__ Sn,
                      int* __restrict__ accCount) {
    int i = blockIdx.x * (blockDim.x >> 6) + (threadIdx.x >> 6);
    int d = threadIdx.x & 63;
    if (i >= nap) return;
    float v = ap[((size_t)i << 6) + d];
    float dsp = v * Sp[d];
    float dse = v * v;
    float dsn = v * Sn[d];
#pragma unroll
    for (int o = 32; o >= 1; o >>= 1) {
        dsp += __shfl_xor(dsp, o, 64);
        dse += __shfl_xor(dse, o, 64);
        dsn += __shfl_xor(dsn, o, 64);
    }
    if (d == 0) {
        float per_pos = (dsp - dse) / (float)(nap - 1);
        float per_neg = dsn / (float)nan_;
        if (per_pos > per_neg) atomicAdd(accCount, 1);
    }
}

// ---------------- mask positive ratio ----------------
__global__ void k_mask(const float* __restrict__ mask, int n, int* __restrict__ cnt) {
    int t = blockIdx.x * blockDim.x + threadIdx.x;
    int local = 0;
    for (int i = t; i < n; i += gridDim.x * blockDim.x) local += (mask[i] > 0.5f) ? 1 : 0;
#pragma unroll
    for (int o = 32; o >= 1; o >>= 1) local += __shfl_xor(local, o, 64);
    __shared__ int red[4];
    if ((threadIdx.x & 63) == 0) red[threadIdx.x >> 6] = local;
    __syncthreads();
    if (threadIdx.x == 0) atomicAdd(cnt, red[0] + red[1] + red[2] + red[3]);
}

__global__ void k_init(int* p) {
    if (threadIdx.x < 2) p[threadIdx.x] = 0;
}

__global__ void k_out(const float* __restrict__ lossPartial, int nb, int A,
                      const int* __restrict__ accCount, int nap,
                      const int* __restrict__ maskCount, int n,
                      float* __restrict__ out) {
    if (threadIdx.x != 0 || blockIdx.x != 0) return;
    float ls = 0.f;
    for (int k = 0; k < nb; ++k) ls += lossPartial[k];
    out[0] = ls / (float)A;
    out[1] = (float)(*accCount) / (float)nap;
    out[2] = (float)(*maskCount) / (float)n;
}

extern "C" void kernel_launch(void* const* d_in, const int* in_sizes, int n_in,
                              void* d_out, int out_size, void* d_ws, size_t ws_size,
                              hipStream_t stream) {
    const float* z        = (const float*)d_in[0];
    const float* mask     = (const float*)d_in[1];
    const int* pos_idx    = (const int*)d_in[2];
    const int* anchor_idx = (const int*)d_in[3];
    const int* neg_idx    = (const int*)d_in[4];
    const int* acc_pos_idx= (const int*)d_in[5];
    const int* acc_neg_idx= (const int*)d_in[6];
    float* out = (float*)d_out;

    const int N   = in_sizes[1];
    const int P   = in_sizes[2];
    const int A   = in_sizes[3];
    const int S   = in_sizes[4];
    const int NAP = in_sizes[5];
    const int NAN_= in_sizes[6];

    float* ws = (float*)d_ws;
    size_t off = 0;
    float* posN = ws + off; off += (size_t)P * 64;
    float* negN = ws + off; off += (size_t)S * 64;
    float* ancN = ws + off; off += (size_t)A * 64;
    float* apN  = ws + off; off += (size_t)NAP * 64;
    float* anN  = ws + off; off += (size_t)NAN_ * 64;
    float* posmax = ws + off; off += (size_t)NCP * A;
    float* negsum = ws + off; off += (size_t)NCN * A;
    float* lossPartial = ws + off; off += 64;
    float* spPart = ws + off; off += (size_t)NB_AP * 64;
    float* snPart = ws + off; off += (size_t)NB_AN * 64;
    float* Sp = ws + off; off += 64;
    float* Sn = ws + off; off += 64;
    int* counters = (int*)(ws + off); // [0]=accCount [1]=maskCount

    k_init<<<1, 64, 0, stream>>>(counters);

    // normalize gathers
    k_norm<<<dim3((P + 3) / 4), 256, 0, stream>>>(z, pos_idx, P, posN);
    k_norm<<<dim3((S + 3) / 4), 256, 0, stream>>>(z, neg_idx, S, negN);
    k_norm<<<dim3((NAP + 3) / 4), 256, 0, stream>>>(z, acc_pos_idx, NAP, apN);
    k_norm<<<dim3((NAN_ + 3) / 4), 256, 0, stream>>>(z, acc_neg_idx, NAN_, anN);

    k_gather<<<dim3((A * 64 + 255) / 256), 256, 0, stream>>>(posN, anchor_idx, A, ancN);

    // similarity reductions
    int atiles = (A + 63) / 64;
    int ablk = (atiles + 3) / 4;
    k_sim<0><<<dim3(ablk, NCP), 256, 0, stream>>>(ancN, A, posN, P, posmax);
    k_sim<1><<<dim3(ablk, NCN), 256, 0, stream>>>(ancN, A, negN, S, negsum);

    int nLossBlk = (A + 255) / 256;
    k_combine<<<dim3(nLossBlk), 256, 0, stream>>>(posmax, NCP, negsum, NCN, A, lossPartial);

    // accuracy path
    k_colsum<<<dim3(NB_AP), 256, 0, stream>>>(apN, NAP, spPart);
    k_colsum_final<<<1, 64, 0, stream>>>(spPart, NB_AP, Sp);
    k_colsum<<<dim3(NB_AN), 256, 0, stream>>>(anN, NAN_, snPart);
    k_colsum_final<<<1, 64, 0, stream>>>(snPart, NB_AN, Sn);
    k_acc<<<dim3((NAP + 3) / 4), 256, 0, stream>>>(apN, NAP, NAN_, Sp, Sn, counters);

    k_mask<<<dim3(256), 256, 0, stream>>>(mask, N, counters + 1);

    k_out<<<1, 64, 0, stream>>>(lossPartial, nLossBlk, A, counters, NAP, counters + 1, N, out);
}

// Round 7
// 668.067 us; speedup vs baseline: 2.4809x; 2.4809x over previous
//
// Retry #5 — rounds 2-6 all ENOSPC inside hipcc. This round: minimized
// translation unit (dropped the z-transpose path entirely) to shrink the
// compiler's output in case free disk is fluctuating near zero.
#include <hip/hip_runtime.h>
#include <math.h>

#define HW_SHIFT 14           // H*W = 16384 (B=8, H=W=128 fixed instance)
#define HW_MASK 16383
#define TEMP_INV 14.285714285714285714f   // 1/0.07
#define M0F TEMP_INV

#define NCP 32   // pos chunks
#define NCN 64   // neg chunks
#define NB_AP 16
#define NB_AN 64

typedef __attribute__((ext_vector_type(8))) short short8v;
typedef __attribute__((ext_vector_type(4))) float f32x4;

__device__ inline ushort f2bf(float f) {
    uint u = __float_as_uint(f);
    return (ushort)((u + 0x7FFFu + ((u >> 16) & 1u)) >> 16);
}
__device__ inline float bf2f(ushort b) { return __uint_as_float((uint)b << 16); }

// ---- gather + L2 normalize -> bf16 [hi|lo] cat rows (and optional fp32 rows) ----
__global__ void k_norm_cat(const float* __restrict__ z, const int* __restrict__ idx,
                           int count, ushort* __restrict__ outCat) {
    int lane = threadIdx.x & 63;
    int wstride = (blockDim.x >> 6) * gridDim.x;
    for (int w = blockIdx.x * (blockDim.x >> 6) + (threadIdx.x >> 6); w < count; w += wstride) {
        int n = idx[w];
        int b = n >> HW_SHIFT;
        int hw = n & HW_MASK;
        float v = z[((size_t)(b * 64 + lane) << HW_SHIFT) + hw];
        float ss = v * v;
#pragma unroll
        for (int o = 32; o >= 1; o >>= 1) ss += __shfl_xor(ss, o, 64);
        float x = v / fmaxf(sqrtf(ss), 1e-12f);
        ushort hi = f2bf(x);
        outCat[(size_t)w * 128 + lane] = hi;
        outCat[(size_t)w * 128 + 64 + lane] = f2bf(x - bf2f(hi));
    }
}

__global__ void k_norm_f32(const float* __restrict__ z, const int* __restrict__ idx,
                           int count, float* __restrict__ out) {
    int lane = threadIdx.x & 63;
    int wstride = (blockDim.x >> 6) * gridDim.x;
    for (int w = blockIdx.x * (blockDim.x >> 6) + (threadIdx.x >> 6); w < count; w += wstride) {
        int n = idx[w];
        int b = n >> HW_SHIFT;
        int hw = n & HW_MASK;
        float v = z[((size_t)(b * 64 + lane) << HW_SHIFT) + hw];
        float ss = v * v;
#pragma unroll
        for (int o = 32; o >= 1; o >>= 1) ss += __shfl_xor(ss, o, 64);
        out[((size_t)w << 6) + lane] = v / fmaxf(sqrtf(ss), 1e-12f);
    }
}

// ---- MFMA similarity: anchors (gathered via aidx) x candidates ----
// rows = 128 bf16 [hi 64 | lo 64]; dot = hihi + hilo + lohi
// MODE 0: max over cands excluding cand ordinal == anchor ordinal
// MODE 1: sum of exp(logit - M0)
template <int MODE>
__global__ void __launch_bounds__(256) k_sim_mfma(
    const ushort* __restrict__ posCat, const int* __restrict__ aidx, int A,
    const ushort* __restrict__ cand, int count, int per,
    float* __restrict__ partial) {
    int wid = threadIdx.x >> 6;
    int lane = threadIdx.x & 63;
    int a0 = (blockIdx.x * 4 + wid) * 16;
    if (a0 >= A) return;
    int chunk = blockIdx.y;
    int c0 = chunk * per;
    int c1 = min(count, c0 + per);
    int ntile = (c1 > c0) ? ((c1 - c0 + 15) >> 4) : 0;

    int lrow = lane & 15;
    int kg = (lane >> 4) * 8;

    int arow = a0 + lrow;
    int asrc = (arow < A) ? aidx[arow] : 0;
    const ushort* aptr = posCat + (size_t)asrc * 128 + kg;
    short8v af[4];
#pragma unroll
    for (int s = 0; s < 4; ++s) af[s] = *(const short8v*)(aptr + 32 * s);

    float rs[4];
#pragma unroll
    for (int e = 0; e < 4; ++e) rs[e] = (MODE == 0) ? -3.0e38f : 0.f;

    const ushort* bp0 = cand + (size_t)(c0 + lrow) * 128 + kg;
    short8v bc[4], bn[4];

    auto loadB = [&](short8v(&b)[4], int t) {
        const ushort* q = bp0 + (size_t)t * 16 * 128;
#pragma unroll
        for (int s = 0; s < 4; ++s) b[s] = *(const short8v*)(q + 32 * s);
    };
    auto compute = [&](const short8v(&b)[4], int t) {
        f32x4 acc = {0.f, 0.f, 0.f, 0.f};
        acc = __builtin_amdgcn_mfma_f32_16x16x32_bf16(af[0], b[0], acc, 0, 0, 0);
        acc = __builtin_amdgcn_mfma_f32_16x16x32_bf16(af[1], b[1], acc, 0, 0, 0);
        acc = __builtin_amdgcn_mfma_f32_16x16x32_bf16(af[0], b[2], acc, 0, 0, 0);
        acc = __builtin_amdgcn_mfma_f32_16x16x32_bf16(af[1], b[3], acc, 0, 0, 0);
        acc = __builtin_amdgcn_mfma_f32_16x16x32_bf16(af[2], b[0], acc, 0, 0, 0);
        acc = __builtin_amdgcn_mfma_f32_16x16x32_bf16(af[3], b[1], acc, 0, 0, 0);
        int colg = c0 + t * 16 + lrow;
        bool colok = colg < count;
#pragma unroll
        for (int e = 0; e < 4; ++e) {
            float l = acc[e] * TEMP_INV;
            if (MODE == 0) {
                int rowg = a0 + (lane >> 4) * 4 + e;
                if (!colok || rowg == colg) l = -3.0e38f;
                rs[e] = fmaxf(rs[e], l);
            } else {
                if (colok) rs[e] += __expf(l - M0F);
            }
        }
    };

    if (ntile > 0) loadB(bc, 0);
    int t = 0;
    for (; t + 1 < ntile; t += 2) {
        loadB(bn, t + 1);
        compute(bc, t);
        if (t + 2 < ntile) loadB(bc, t + 2);
        compute(bn, t + 1);
    }
    if (t < ntile) compute(bc, t);

#pragma unroll
    for (int e = 0; e < 4; ++e) {
        float v = rs[e];
#pragma unroll
        for (int o = 8; o >= 1; o >>= 1) {
            float w = __shfl_xor(v, o, 64);
            v = (MODE == 0) ? fmaxf(v, w) : (v + w);
        }
        rs[e] = v;
    }
    if (lrow == 0) {
        int rbase = a0 + (lane >> 4) * 4;
#pragma unroll
        for (int e = 0; e < 4; ++e)
            if (rbase + e < A) partial[(size_t)chunk * A + rbase + e] = rs[e];
    }
}

// ---- combine partials -> per-block loss sums ----
__global__ void k_combine(const float* __restrict__ posmax, int ncp,
                          const float* __restrict__ negsum, int ncn,
                          int A, float* __restrict__ lossPartial) {
    int a = blockIdx.x * blockDim.x + threadIdx.x;
    float term = 0.f;
    if (a < A) {
        float m = -__builtin_inff();
        for (int k = 0; k < ncp; ++k) m = fmaxf(m, posmax[(size_t)k * A + a]);
        float s = 0.f;
        for (int k = 0; k < ncn; ++k) s += negsum[(size_t)k * A + a];
        term = M0F + logf(__expf(m - M0F) + s) - m;
    }
    __shared__ float red[256];
    red[threadIdx.x] = term;
    __syncthreads();
    for (int o = 128; o >= 1; o >>= 1) {
        if (threadIdx.x < o) red[threadIdx.x] += red[threadIdx.x + o];
        __syncthreads();
    }
    if (threadIdx.x == 0) lossPartial[blockIdx.x] = red[0];
}

// ---- column sums (deterministic two-stage) ----
__global__ void k_colsum(const float* __restrict__ in, int rows, float* __restrict__ partial) {
    int d = threadIdx.x & 63;
    int rg = threadIdx.x >> 6;
    float acc = 0.f;
    for (int r = blockIdx.x * 4 + rg; r < rows; r += gridDim.x * 4)
        acc += in[((size_t)r << 6) + d];
    __shared__ float red[256];
    red[threadIdx.x] = acc;
    __syncthreads();
    if (rg == 0)
        partial[((size_t)blockIdx.x << 6) + d] = (red[d] + red[64 + d]) + (red[128 + d] + red[192 + d]);
}

__global__ void k_colsum_final(const float* __restrict__ partial, int nb, float* __restrict__ out64) {
    int d = threadIdx.x;
    if (d >= 64) return;
    float acc = 0.f;
    for (int k = 0; k < nb; ++k) acc += partial[((size_t)k << 6) + d];
    out64[d] = acc;
}

// ---- accuracy comparisons ----
__global__ void k_acc(const float* __restrict__ ap, int nap, int nan_,
                      const float* __restrict__ Sp, const float* __restrict__ Sn,
                      int* __restrict__ accCount) {
    int i = blockIdx.x * (blockDim.x >> 6) + (threadIdx.x >> 6);
    int d = threadIdx.x & 63;
    if (i >= nap) return;
    float v = ap[((size_t)i << 6) + d];
    float dsp = v * Sp[d];
    float dse = v * v;
    float dsn = v * Sn[d];
#pragma unroll
    for (int o = 32; o >= 1; o >>= 1) {
        dsp += __shfl_xor(dsp, o, 64);
        dse += __shfl_xor(dse, o, 64);
        dsn += __shfl_xor(dsn, o, 64);
    }
    if (d == 0) {
        float per_pos = (dsp - dse) / (float)(nap - 1);
        float per_neg = dsn / (float)nan_;
        if (per_pos > per_neg) atomicAdd(accCount, 1);
    }
}

// ---- mask positive ratio ----
__global__ void k_mask(const float* __restrict__ mask, int n, int* __restrict__ cnt) {
    int t = blockIdx.x * blockDim.x + threadIdx.x;
    int local = 0;
    for (int i = t; i < n; i += gridDim.x * blockDim.x) local += (mask[i] > 0.5f) ? 1 : 0;
#pragma unroll
    for (int o = 32; o >= 1; o >>= 1) local += __shfl_xor(local, o, 64);
    __shared__ int red[4];
    if ((threadIdx.x & 63) == 0) red[threadIdx.x >> 6] = local;
    __syncthreads();
    if (threadIdx.x == 0) atomicAdd(cnt, red[0] + red[1] + red[2] + red[3]);
}

__global__ void k_init(int* p) {
    if (threadIdx.x < 2) p[threadIdx.x] = 0;
}

__global__ void k_out(const float* __restrict__ lossPartial, int nb, int A,
                      const int* __restrict__ accCount, int nap,
                      const int* __restrict__ maskCount, int n,
                      float* __restrict__ out) {
    if (threadIdx.x != 0 || blockIdx.x != 0) return;
    float ls = 0.f;
    for (int k = 0; k < nb; ++k) ls += lossPartial[k];
    out[0] = ls / (float)A;
    out[1] = (float)(*accCount) / (float)nap;
    out[2] = (float)(*maskCount) / (float)n;
}

extern "C" void kernel_launch(void* const* d_in, const int* in_sizes, int n_in,
                              void* d_out, int out_size, void* d_ws, size_t ws_size,
                              hipStream_t stream) {
    const float* z        = (const float*)d_in[0];
    const float* mask     = (const float*)d_in[1];
    const int* pos_idx    = (const int*)d_in[2];
    const int* anchor_idx = (const int*)d_in[3];
    const int* neg_idx    = (const int*)d_in[4];
    const int* acc_pos_idx= (const int*)d_in[5];
    const int* acc_neg_idx= (const int*)d_in[6];
    float* out = (float*)d_out;

    const int N   = in_sizes[1];
    const int P   = in_sizes[2];
    const int A   = in_sizes[3];
    const int S   = in_sizes[4];
    const int NAP = in_sizes[5];
    const int NAN_= in_sizes[6];

    float* ws = (float*)d_ws;
    size_t off = 0;
    auto alloc = [&](size_t floats) { size_t p = off; off += (floats + 63) & ~(size_t)63; return p; };

    size_t o_posCat = alloc((size_t)(P + 16) * 64);
    size_t o_negCat = alloc((size_t)(S + 16) * 64);
    size_t o_apN    = alloc((size_t)NAP * 64);
    size_t o_anN    = alloc((size_t)NAN_ * 64);
    size_t o_posmax = alloc((size_t)NCP * A);
    size_t o_negsum = alloc((size_t)NCN * A);
    size_t o_lossP  = alloc(64);
    size_t o_spPart = alloc((size_t)NB_AP * 64);
    size_t o_snPart = alloc((size_t)NB_AN * 64);
    size_t o_Sp     = alloc(64);
    size_t o_Sn     = alloc(64);
    size_t o_cnt    = alloc(64);

    ushort* posCat = (ushort*)(ws + o_posCat);
    ushort* negCat = (ushort*)(ws + o_negCat);
    float* apN = ws + o_apN;
    float* anN = ws + o_anN;
    float* posmax = ws + o_posmax;
    float* negsum = ws + o_negsum;
    float* lossPartial = ws + o_lossP;
    float* spPart = ws + o_spPart;
    float* snPart = ws + o_snPart;
    float* Sp = ws + o_Sp;
    float* Sn = ws + o_Sn;
    int* counters = (int*)(ws + o_cnt);

    k_init<<<1, 64, 0, stream>>>(counters);

    k_norm_cat<<<dim3(1024), 256, 0, stream>>>(z, pos_idx, P, posCat);
    k_norm_cat<<<dim3(2048), 256, 0, stream>>>(z, neg_idx, S, negCat);
    k_norm_f32<<<dim3(256), 256, 0, stream>>>(z, acc_pos_idx, NAP, apN);
    k_norm_f32<<<dim3(512), 256, 0, stream>>>(z, acc_neg_idx, NAN_, anN);

    int gx = (A + 63) / 64;
    int perP = (P + NCP - 1) / NCP;
    int perN = (S + NCN - 1) / NCN;
    k_sim_mfma<0><<<dim3(gx, NCP), 256, 0, stream>>>(posCat, anchor_idx, A, posCat, P, perP, posmax);
    k_sim_mfma<1><<<dim3(gx, NCN), 256, 0, stream>>>(posCat, anchor_idx, A, negCat, S, perN, negsum);

    int nLossBlk = (A + 255) / 256;
    k_combine<<<dim3(nLossBlk), 256, 0, stream>>>(posmax, NCP, negsum, NCN, A, lossPartial);

    k_colsum<<<dim3(NB_AP), 256, 0, stream>>>(apN, NAP, spPart);
    k_colsum_final<<<1, 64, 0, stream>>>(spPart, NB_AP, Sp);
    k_colsum<<<dim3(NB_AN), 256, 0, stream>>>(anN, NAN_, snPart);
    k_colsum_final<<<1, 64, 0, stream>>>(snPart, NB_AN, Sn);
    k_acc<<<dim3((NAP + 3) / 4), 256, 0, stream>>>(apN, NAP, NAN_, Sp, Sn, counters);

    k_mask<<<dim3(256), 256, 0, stream>>>(mask, N, counters + 1);

    k_out<<<1, 64, 0, stream>>>(lossPartial, nLossBlk, A, counters, NAP, counters + 1, N, out);
}

// Round 9
// 307.749 us; speedup vs baseline: 5.3855x; 2.1708x over previous
//
// R9: fix post-timing divergence (race). R8's dbuf+single-barrier prefetch
// schedule was a new sync structure (m152: naive combos race). Retreat to the
// verified m97 pattern: single LDS buffer, stage -> sync -> compute -> sync.
// Swizzle + AF=4 tiling + exp2 epilogue retained (first-call-correct in R8).
#include <hip/hip_runtime.h>
#include <math.h>

#define HW_SHIFT 14           // H*W = 16384 (B=8, H=W=128 fixed instance)
#define HW_MASK 16383
#define TEMP_INV 14.285714285714285714f   // 1/0.07
#define M0F TEMP_INV
#define CEXP_S 20.609929155556627f        // TEMP_INV * log2(e)
#define CEXP_B (-20.609929155556627f)     // -M0 * log2(e)

#define NCP 32   // pos chunks
#define NCN 64   // neg chunks
#define NB_AP 16
#define NB_AN 64
#define AF 4     // anchor fragment groups per wave (64 anchors/wave)

typedef __attribute__((ext_vector_type(8))) short short8v;
typedef __attribute__((ext_vector_type(4))) float f32x4;

__device__ inline ushort f2bf(float f) {
    uint u = __float_as_uint(f);
    return (ushort)((u + 0x7FFFu + ((u >> 16) & 1u)) >> 16);
}
__device__ inline float bf2f(ushort b) { return __uint_as_float((uint)b << 16); }

#define GLOAD_LDS16(g, l) __builtin_amdgcn_global_load_lds( \
    (const __attribute__((address_space(1))) void*)(g), \
    (__attribute__((address_space(3))) void*)(l), 16, 0, 0)

// ---- gather + L2 normalize -> bf16 [hi|lo] cat rows ----
__global__ void k_norm_cat(const float* __restrict__ z, const int* __restrict__ idx,
                           int count, ushort* __restrict__ outCat) {
    int lane = threadIdx.x & 63;
    int wstride = (blockDim.x >> 6) * gridDim.x;
    for (int w = blockIdx.x * (blockDim.x >> 6) + (threadIdx.x >> 6); w < count; w += wstride) {
        int n = idx[w];
        int b = n >> HW_SHIFT;
        int hw = n & HW_MASK;
        float v = z[((size_t)(b * 64 + lane) << HW_SHIFT) + hw];
        float ss = v * v;
#pragma unroll
        for (int o = 32; o >= 1; o >>= 1) ss += __shfl_xor(ss, o, 64);
        float x = v / fmaxf(sqrtf(ss), 1e-12f);
        ushort hi = f2bf(x);
        outCat[(size_t)w * 128 + lane] = hi;
        outCat[(size_t)w * 128 + 64 + lane] = f2bf(x - bf2f(hi));
    }
}

__global__ void k_norm_f32(const float* __restrict__ z, const int* __restrict__ idx,
                           int count, float* __restrict__ out) {
    int lane = threadIdx.x & 63;
    int wstride = (blockDim.x >> 6) * gridDim.x;
    for (int w = blockIdx.x * (blockDim.x >> 6) + (threadIdx.x >> 6); w < count; w += wstride) {
        int n = idx[w];
        int b = n >> HW_SHIFT;
        int hw = n & HW_MASK;
        float v = z[((size_t)(b * 64 + lane) << HW_SHIFT) + hw];
        float ss = v * v;
#pragma unroll
        for (int o = 32; o >= 1; o >>= 1) ss += __shfl_xor(ss, o, 64);
        out[((size_t)w << 6) + lane] = v / fmaxf(sqrtf(ss), 1e-12f);
    }
}

// ---- tiled MFMA similarity: 256 anchors/block (64/wave), LDS-staged B ----
// rows = 128 bf16 [hi 64 | lo 64]; dot = hihi + hilo + lohi
// MODE 0: max over cands excluding cand ordinal == anchor ordinal
// MODE 1: sum of exp2(logit*log2e - M0*log2e)
template <int MODE>
__global__ void __launch_bounds__(256) k_sim_mfma(
    const ushort* __restrict__ posCat, const int* __restrict__ aidx, int A,
    const ushort* __restrict__ cand, int count, int per,
    float* __restrict__ partial) {
    __shared__ __align__(16) char ldsB[8192];   // 32 cands x 256B, single buffer

    int wid = threadIdx.x >> 6;
    int lane = threadIdx.x & 63;
    int lrow = lane & 15;
    int q = lane >> 4;
    int a0 = blockIdx.x * 256 + wid * 64;     // wave's 64 anchors
    int chunk = blockIdx.y;
    int c0 = chunk * per;
    int c1 = min(count, c0 + per);
    int nsteps = (c1 > c0) ? ((c1 - c0 + 31) >> 5) : 0;

    // A fragments: AF groups x 4 k-frags, pinned in VGPRs
    short8v af[AF][4];
#pragma unroll
    for (int g = 0; g < AF; ++g) {
        int arow = a0 + g * 16 + lrow;
        int asrc = aidx[min(arow, A - 1)];
        const ushort* aptr = posCat + (size_t)asrc * 128 + q * 8;
#pragma unroll
        for (int s = 0; s < 4; ++s) af[g][s] = *(const short8v*)(aptr + 32 * s);
    }

    float rs[AF][4];
#pragma unroll
    for (int g = 0; g < AF; ++g)
#pragma unroll
        for (int e = 0; e < 4; ++e) rs[g][e] = (MODE == 0) ? -3.0e38f : 0.f;

    // stage 32 cands (8KB): linear LDS dest, pre-swizzled global src (rule 21)
    auto stage = [&](int t) {
        const char* gsrc = (const char*)cand + (size_t)(c0 + t * 32) * 256;
#pragma unroll
        for (int i = 0; i < 2; ++i) {
            uint ubase = (uint)i * 4096u + (uint)wid * 1024u;   // wave-uniform
            uint o = ubase + (uint)lane * 16u;
            uint row = o >> 8;
            uint src = o ^ ((row & 7u) << 4);
            GLOAD_LDS16(gsrc + src, ldsB + ubase);
        }
    };

    auto computeTile = [&](int t16, int tglob) {
        short8v b[4];
#pragma unroll
        for (int s = 0; s < 4; ++s) {
            uint row = (uint)(t16 * 16 + lrow);
            uint col = (uint)(q * 16 + s * 64);
            uint addr = row * 256u + (col ^ ((row & 7u) << 4));
            b[s] = *(const short8v*)(ldsB + addr);
        }
        int colg = c0 + tglob * 16 + lrow;
        bool colok = colg < c1;
#pragma unroll
        for (int g = 0; g < AF; ++g) {
            f32x4 acc = {0.f, 0.f, 0.f, 0.f};
            acc = __builtin_amdgcn_mfma_f32_16x16x32_bf16(af[g][0], b[0], acc, 0, 0, 0);
            acc = __builtin_amdgcn_mfma_f32_16x16x32_bf16(af[g][1], b[1], acc, 0, 0, 0);
            acc = __builtin_amdgcn_mfma_f32_16x16x32_bf16(af[g][0], b[2], acc, 0, 0, 0);
            acc = __builtin_amdgcn_mfma_f32_16x16x32_bf16(af[g][1], b[3], acc, 0, 0, 0);
            acc = __builtin_amdgcn_mfma_f32_16x16x32_bf16(af[g][2], b[0], acc, 0, 0, 0);
            acc = __builtin_amdgcn_mfma_f32_16x16x32_bf16(af[g][3], b[1], acc, 0, 0, 0);
#pragma unroll
            for (int e = 0; e < 4; ++e) {
                if (MODE == 0) {
                    int rowg = a0 + g * 16 + q * 4 + e;
                    float l = acc[e] * TEMP_INV;
                    if (!colok || rowg == colg) l = -3.0e38f;
                    rs[g][e] = fmaxf(rs[g][e], l);
                } else {
                    float p = exp2f(__fmaf_rn(acc[e], CEXP_S, CEXP_B));
                    rs[g][e] += colok ? p : 0.f;
                }
            }
        }
    };

    // m97 verified structure: stage -> sync -> compute -> sync (single buffer)
    for (int t = 0; t < nsteps; ++t) {
        stage(t);
        __syncthreads();            // drains vmcnt: LDS tile complete
        computeTile(0, 2 * t);
        computeTile(1, 2 * t + 1);
        __syncthreads();            // all waves done reading before next overwrite
    }

    // reduce across the 16-lane column group, write per-chunk partials
#pragma unroll
    for (int g = 0; g < AF; ++g) {
#pragma unroll
        for (int e = 0; e < 4; ++e) {
            float v = rs[g][e];
#pragma unroll
            for (int o = 8; o >= 1; o >>= 1) {
                float w = __shfl_xor(v, o, 64);
                v = (MODE == 0) ? fmaxf(v, w) : (v + w);
            }
            rs[g][e] = v;
        }
        if (lrow == 0) {
            int rbase = a0 + g * 16 + q * 4;
#pragma unroll
            for (int e = 0; e < 4; ++e)
                if (rbase + e < A) partial[(size_t)chunk * A + rbase + e] = rs[g][e];
        }
    }
}

// ---- combine partials -> per-block loss sums ----
__global__ void k_combine(const float* __restrict__ posmax, int ncp,
                          const float* __restrict__ negsum, int ncn,
                          int A, float* __restrict__ lossPartial) {
    int a = blockIdx.x * blockDim.x + threadIdx.x;
    float term = 0.f;
    if (a < A) {
        float m = -__builtin_inff();
        for (int k = 0; k < ncp; ++k) m = fmaxf(m, posmax[(size_t)k * A + a]);
        float s = 0.f;
        for (int k = 0; k < ncn; ++k) s += negsum[(size_t)k * A + a];
        term = M0F + logf(__expf(m - M0F) + s) - m;
    }
    __shared__ float red[256];
    red[threadIdx.x] = term;
    __syncthreads();
    for (int o = 128; o >= 1; o >>= 1) {
        if (threadIdx.x < o) red[threadIdx.x] += red[threadIdx.x + o];
        __syncthreads();
    }
    if (threadIdx.x == 0) lossPartial[blockIdx.x] = red[0];
}

// ---- column sums (deterministic two-stage) ----
__global__ void k_colsum(const float* __restrict__ in, int rows, float* __restrict__ partial) {
    int d = threadIdx.x & 63;
    int rg = threadIdx.x >> 6;
    float acc = 0.f;
    for (int r = blockIdx.x * 4 + rg; r < rows; r += gridDim.x * 4)
        acc += in[((size_t)r << 6) + d];
    __shared__ float red[256];
    red[threadIdx.x] = acc;
    __syncthreads();
    if (rg == 0)
        partial[((size_t)blockIdx.x << 6) + d] = (red[d] + red[64 + d]) + (red[128 + d] + red[192 + d]);
}

__global__ void k_colsum_final(const float* __restrict__ partial, int nb, float* __restrict__ out64) {
    int d = threadIdx.x;
    if (d >= 64) return;
    float acc = 0.f;
    for (int k = 0; k < nb; ++k) acc += partial[((size_t)k << 6) + d];
    out64[d] = acc;
}

// ---- accuracy comparisons ----
__global__ void k_acc(const float* __restrict__ ap, int nap, int nan_,
                      const float* __restrict__ Sp, const float* __restrict__ Sn,
                      int* __restrict__ accCount) {
    int i = blockIdx.x * (blockDim.x >> 6) + (threadIdx.x >> 6);
    int d = threadIdx.x & 63;
    if (i >= nap) return;
    float v = ap[((size_t)i << 6) + d];
    float dsp = v * Sp[d];
    float dse = v * v;
    float dsn = v * Sn[d];
#pragma unroll
    for (int o = 32; o >= 1; o >>= 1) {
        dsp += __shfl_xor(dsp, o, 64);
        dse += __shfl_xor(dse, o, 64);
        dsn += __shfl_xor(dsn, o, 64);
    }
    if (d == 0) {
        float per_pos = (dsp - dse) / (float)(nap - 1);
        float per_neg = dsn / (float)nan_;
        if (per_pos > per_neg) atomicAdd(accCount, 1);
    }
}

// ---- mask positive ratio ----
__global__ void k_mask(const float* __restrict__ mask, int n, int* __restrict__ cnt) {
    int t = blockIdx.x * blockDim.x + threadIdx.x;
    int local = 0;
    for (int i = t; i < n; i += gridDim.x * blockDim.x) local += (mask[i] > 0.5f) ? 1 : 0;
#pragma unroll
    for (int o = 32; o >= 1; o >>= 1) local += __shfl_xor(local, o, 64);
    __shared__ int red[4];
    if ((threadIdx.x & 63) == 0) red[threadIdx.x >> 6] = local;
    __syncthreads();
    if (threadIdx.x == 0) atomicAdd(cnt, red[0] + red[1] + red[2] + red[3]);
}

__global__ void k_init(int* p) {
    if (threadIdx.x < 2) p[threadIdx.x] = 0;
}

__global__ void k_out(const float* __restrict__ lossPartial, int nb, int A,
                      const int* __restrict__ accCount, int nap,
                      const int* __restrict__ maskCount, int n,
                      float* __restrict__ out) {
    if (threadIdx.x != 0 || blockIdx.x != 0) return;
    float ls = 0.f;
    for (int k = 0; k < nb; ++k) ls += lossPartial[k];
    out[0] = ls / (float)A;
    out[1] = (float)(*accCount) / (float)nap;
    out[2] = (float)(*maskCount) / (float)n;
}

extern "C" void kernel_launch(void* const* d_in, const int* in_sizes, int n_in,
                              void* d_out, int out_size, void* d_ws, size_t ws_size,
                              hipStream_t stream) {
    const float* z        = (const float*)d_in[0];
    const float* mask     = (const float*)d_in[1];
    const int* pos_idx    = (const int*)d_in[2];
    const int* anchor_idx = (const int*)d_in[3];
    const int* neg_idx    = (const int*)d_in[4];
    const int* acc_pos_idx= (const int*)d_in[5];
    const int* acc_neg_idx= (const int*)d_in[6];
    float* out = (float*)d_out;

    const int N   = in_sizes[1];
    const int P   = in_sizes[2];
    const int A   = in_sizes[3];
    const int S   = in_sizes[4];
    const int NAP = in_sizes[5];
    const int NAN_= in_sizes[6];

    float* ws = (float*)d_ws;
    size_t off = 0;
    auto alloc = [&](size_t floats) { size_t p = off; off += (floats + 63) & ~(size_t)63; return p; };

    size_t o_posCat = alloc((size_t)(P + 32) * 64);   // +32 rows staging pad
    size_t o_negCat = alloc((size_t)(S + 32) * 64);
    size_t o_apN    = alloc((size_t)NAP * 64);
    size_t o_anN    = alloc((size_t)NAN_ * 64);
    size_t o_posmax = alloc((size_t)NCP * A);
    size_t o_negsum = alloc((size_t)NCN * A);
    size_t o_lossP  = alloc(64);
    size_t o_spPart = alloc((size_t)NB_AP * 64);
    size_t o_snPart = alloc((size_t)NB_AN * 64);
    size_t o_Sp     = alloc(64);
    size_t o_Sn     = alloc(64);
    size_t o_cnt    = alloc(64);

    ushort* posCat = (ushort*)(ws + o_posCat);
    ushort* negCat = (ushort*)(ws + o_negCat);
    float* apN = ws + o_apN;
    float* anN = ws + o_anN;
    float* posmax = ws + o_posmax;
    float* negsum = ws + o_negsum;
    float* lossPartial = ws + o_lossP;
    float* spPart = ws + o_spPart;
    float* snPart = ws + o_snPart;
    float* Sp = ws + o_Sp;
    float* Sn = ws + o_Sn;
    int* counters = (int*)(ws + o_cnt);

    k_init<<<1, 64, 0, stream>>>(counters);

    k_norm_cat<<<dim3(1024), 256, 0, stream>>>(z, pos_idx, P, posCat);
    k_norm_cat<<<dim3(2048), 256, 0, stream>>>(z, neg_idx, S, negCat);
    k_norm_f32<<<dim3(256), 256, 0, stream>>>(z, acc_pos_idx, NAP, apN);
    k_norm_f32<<<dim3(512), 256, 0, stream>>>(z, acc_neg_idx, NAN_, anN);

    int gx = (A + 255) / 256;
    int perP = (P + NCP - 1) / NCP;
    int perN = (S + NCN - 1) / NCN;
    k_sim_mfma<0><<<dim3(gx, NCP), 256, 0, stream>>>(posCat, anchor_idx, A, posCat, P, perP, posmax);
    k_sim_mfma<1><<<dim3(gx, NCN), 256, 0, stream>>>(posCat, anchor_idx, A, negCat, S, perN, negsum);

    int nLossBlk = (A + 255) / 256;
    k_combine<<<dim3(nLossBlk), 256, 0, stream>>>(posmax, NCP, negsum, NCN, A, lossPartial);

    k_colsum<<<dim3(NB_AP), 256, 0, stream>>>(apN, NAP, spPart);
    k_colsum_final<<<1, 64, 0, stream>>>(spPart, NB_AP, Sp);
    k_colsum<<<dim3(NB_AN), 256, 0, stream>>>(anN, NAN_, snPart);
    k_colsum_final<<<1, 64, 0, stream>>>(snPart, NB_AN, Sn);
    k_acc<<<dim3((NAP + 3) / 4), 256, 0, stream>>>(apN, NAP, NAN_, Sp, Sn, counters);

    k_mask<<<dim3(256), 256, 0, stream>>>(mask, N, counters + 1);

    k_out<<<1, 64, 0, stream>>>(lossPartial, nLossBlk, A, counters, NAP, counters + 1, N, out);
}